// Round 4
// baseline (251.513 us; speedup 1.0000x reference)
//
#include <hip/hip_runtime.h>
#include <hip/hip_bf16.h>

#define DIMN 2048
#define NQKV 6144
#define NH 16
#define HD 128
#define BSZ 2
#define SEQ 2048
#define ROWS (BSZ*SEQ)   // 4096

typedef short short8 __attribute__((ext_vector_type(8)));
typedef float f32x4 __attribute__((ext_vector_type(4)));

__device__ __forceinline__ unsigned short f2bf(float f) {
    __hip_bfloat16 h = __float2bfloat16(f);
    unsigned short u; __builtin_memcpy(&u, &h, 2); return u;
}

__device__ __forceinline__ void gld_lds16(const void* g, void* l) {
    __builtin_amdgcn_global_load_lds(
        (const __attribute__((address_space(1))) void*)g,
        (__attribute__((address_space(3))) void*)l, 16, 0, 0);
}

// ---------------- fused f32 -> bf16 converts (x, wq|wk|wv -> Wcat, wo) ----------------
__global__ void cvt_all(const float* __restrict__ x, const float* __restrict__ wq,
                        const float* __restrict__ wk, const float* __restrict__ wv,
                        const float* __restrict__ wo,
                        unsigned short* __restrict__ Xb, unsigned short* __restrict__ Wcat,
                        unsigned short* __restrict__ Wo2) {
    int bid = blockIdx.x;
    const float* in; unsigned short* out; int base;
    if      (bid <  8192) { in = x;  out = Xb;             base = bid; }
    else if (bid < 12288) { in = wq; out = Wcat;           base = bid - 8192; }
    else if (bid < 16384) { in = wk; out = Wcat + 4194304; base = bid - 12288; }
    else if (bid < 20480) { in = wv; out = Wcat + 8388608; base = bid - 16384; }
    else                  { in = wo; out = Wo2;            base = bid - 20480; }
    int i = (base * 256 + threadIdx.x) * 4;
    float4 v = *(const float4*)(in + i);
    ushort4 o; o.x = f2bf(v.x); o.y = f2bf(v.y); o.z = f2bf(v.z); o.w = f2bf(v.w);
    *(ushort4*)(out + i) = o;
}

// ================= pipelined GEMM: C[m][n] = sum_k A[m][k]*B[n][k] =================
// BM=256, BN=128, BK=64. 512 threads, 8 waves (2M x 4N), per-wave output 128x32
// (MREP=8, NREP=2) -> LDS read 20KB/wave/K-tile = 19 B/kFLOP (was 32 at 64x64/wave).
// LDS: As[2 dbuf][2 half][128][64], Bs[2 dbuf][2 half][64][64] = 96 KiB.
// 4 sub-phases per K-tile: ph0 {B frags(4) + A mi0-1(4) reads}, ph1 {A mi2-3 + stage A0(kt+1)},
// ph2 {A mi4-5 + stage A1(kt+1)}, ph3 {A mi6-7 + stage B(kt+2)}; 8 MFMA per phase;
// ONE barrier per phase; ONE trailing vmcnt(2) per K-tile (A(kt+1) retired, B(kt+2) in flight).
// Write-after-read safety: a slot's last reads complete at that phase's lgkmcnt(0), which
// precedes the phase barrier; all stage-issues into that slot happen after a later barrier.
// Swizzle: 16B-col' = col16 ^ (row&7) on 128B rows -> 0 bank conflicts (measured r2/r3);
// source pre-swizzled so global_load_lds dest stays linear.
// MODE 0: bf16 out + QKV region bias + fused RoPE. MODE 1: f32 out + bias, B selected per batch.

#define LA(O) (*(const short8*)&As[O])
#define LB(O) (*(const short8*)&Bs[O])
#define STAGE_A(KT, H) do { \
    gld_lds16(aS + (size_t)((H)*128)*lda + (size_t)(KT)*64,    &As[(((KT)&1)<<14) + ((H)<<13) + t8]); \
    gld_lds16(aS + (size_t)((H)*128+64)*lda + (size_t)(KT)*64, &As[(((KT)&1)<<14) + ((H)<<13) + 4096 + t8]); \
  } while (0)
#define STAGE_B(KT, H) \
    gld_lds16(bS + (size_t)((H)*64)*ldb + (size_t)(KT)*64, &Bs[(((KT)&1)<<13) + ((H)<<12) + t8])

#define PH_MFMA(MB) do { \
    asm volatile("s_waitcnt lgkmcnt(0)"); \
    __builtin_amdgcn_sched_barrier(0); \
    __builtin_amdgcn_s_setprio(1); \
    _Pragma("unroll") \
    for (int ni = 0; ni < 2; ++ni) { \
      acc[MB][ni]     = __builtin_amdgcn_mfma_f32_16x16x32_bf16(aa0[0], b_[ni][0], acc[MB][ni], 0, 0, 0); \
      acc[MB][ni]     = __builtin_amdgcn_mfma_f32_16x16x32_bf16(aa0[1], b_[ni][1], acc[MB][ni], 0, 0, 0); \
      acc[(MB)+1][ni] = __builtin_amdgcn_mfma_f32_16x16x32_bf16(aa1[0], b_[ni][0], acc[(MB)+1][ni], 0, 0, 0); \
      acc[(MB)+1][ni] = __builtin_amdgcn_mfma_f32_16x16x32_bf16(aa1[1], b_[ni][1], acc[(MB)+1][ni], 0, 0, 0); \
    } \
    __builtin_amdgcn_s_setprio(0); \
    __builtin_amdgcn_sched_barrier(0); \
  } while (0)

#define PH_BAR() do { asm volatile("s_barrier"); __builtin_amdgcn_sched_barrier(0); } while (0)

#define TR2 asm volatile("s_waitcnt vmcnt(2)"); __builtin_amdgcn_sched_barrier(0);
#define TR0 asm volatile("s_waitcnt vmcnt(0)"); __builtin_amdgcn_sched_barrier(0);
#define TRN

#define KTILE(KT, D, SA, SB, TRAILOP) do { \
    const int dA = (D) << 14, dB = (D) << 13; \
    short8 b_[2][2], aa0[2], aa1[2]; \
    b_[0][0] = LB(dB + bR);        b_[0][1] = LB(dB + (bR ^ 32)); \
    b_[1][0] = LB(dB + bR + 1024); b_[1][1] = LB(dB + (bR ^ 32) + 1024); \
    aa0[0] = LA(dA + aR);          aa0[1] = LA(dA + (aR ^ 32)); \
    aa1[0] = LA(dA + aR + 1024);   aa1[1] = LA(dA + (aR ^ 32) + 1024); \
    PH_MFMA(0); PH_BAR(); \
    aa0[0] = LA(dA + aR + 2048);   aa0[1] = LA(dA + (aR ^ 32) + 2048); \
    aa1[0] = LA(dA + aR + 3072);   aa1[1] = LA(dA + (aR ^ 32) + 3072); \
    if (SA) STAGE_A((KT) + 1, 0); \
    PH_MFMA(2); PH_BAR(); \
    aa0[0] = LA(dA + aR + 4096);   aa0[1] = LA(dA + (aR ^ 32) + 4096); \
    aa1[0] = LA(dA + aR + 5120);   aa1[1] = LA(dA + (aR ^ 32) + 5120); \
    if (SA) STAGE_A((KT) + 1, 1); \
    PH_MFMA(4); PH_BAR(); \
    aa0[0] = LA(dA + aR + 6144);   aa0[1] = LA(dA + (aR ^ 32) + 6144); \
    aa1[0] = LA(dA + aR + 7168);   aa1[1] = LA(dA + (aR ^ 32) + 7168); \
    if (SB) { STAGE_B((KT) + 2, 0); STAGE_B((KT) + 2, 1); } \
    PH_MFMA(6); \
    TRAILOP \
    PH_BAR(); \
  } while (0)

template<int MODE>
__global__ __launch_bounds__(512, 2) void gemm_p4(
    const unsigned short* __restrict__ A, int lda,
    const unsigned short* __restrict__ B, int ldb,
    const float* __restrict__ b0, const float* __restrict__ b1, const float* __restrict__ b2,
    const float* __restrict__ fcos, const float* __restrict__ fsin,
    void* __restrict__ C, int ldc, int K)
{
    __shared__ __align__(16) unsigned short As[32768];  // 64 KiB
    __shared__ __align__(16) unsigned short Bs[16384];  // 32 KiB

    const int t  = threadIdx.x;
    const int l  = t & 63;
    const int w  = t >> 6;
    const int wr = w >> 2;          // 0..1  (M half)
    const int wc = w & 3;           // 0..3  (N quarter, 32 cols)
    const int fr = l & 15, fq = l >> 4;
    const int t8 = t * 8;

    // XCD-aware bijective swizzle (nwg % 8 == 0 for both grids)
    const int gx  = gridDim.x;
    const int lin = blockIdx.y * gx + blockIdx.x;
    const int cpx = (gx * gridDim.y) >> 3;
    const int u   = (lin & 7) * cpx + (lin >> 3);
    const int n0  = (u % gx) * 128;
    const int m0  = (u / gx) * 256;

    const unsigned short* Bsel = B;
    if (MODE == 1 && m0 >= 2048) Bsel += (size_t)2048 * 2048;  // per-batch W2

    // staging sources (pre-swizzled col so linear LDS dest matches swizzled reads)
    const int sr  = t >> 3;
    const int scw = ((t & 7) ^ (sr & 7)) * 8;
    const unsigned short* aS = A    + (size_t)(m0 + sr) * lda + scw;
    const unsigned short* bS = Bsel + (size_t)(n0 + sr) * ldb + scw;

    // fragment read bases (element offsets); kk=1 = ^32
    const int c0 = fq ^ (fr & 7);
    const int aR = wr * 8192 + fr * 64 + c0 * 8;   // + mi*1024
    const int bR = wc * 2048 + fr * 64 + c0 * 8;   // + ni*1024

    f32x4 acc[8][2] = {};

    const int ktT = K >> 6;   // 32

    // prologue: A(0), B(0), B(1) staged; wait A(0)+B(0) (leave B(1)'s 2 in flight)
    STAGE_A(0, 0); STAGE_A(0, 1);
    STAGE_B(0, 0); STAGE_B(0, 1);
    STAGE_B(1, 0); STAGE_B(1, 1);
    asm volatile("s_waitcnt vmcnt(2)");
    __builtin_amdgcn_sched_barrier(0);
    PH_BAR();

    for (int kt = 0; kt < ktT - 2; kt += 2) {
        KTILE(kt,     0, 1, 1, TR2);
        KTILE(kt + 1, 1, 1, 1, TR2);
    }
    KTILE(ktT - 2, 0, 1, 0, TR0);
    KTILE(ktT - 1, 1, 0, 0, TRN);

    // ---- epilogue
    #pragma unroll
    for (int mi = 0; mi < 8; ++mi) {
        #pragma unroll
        for (int ni = 0; ni < 2; ++ni) {
            #pragma unroll
            for (int j = 0; j < 4; ++j) {
                const int r  = m0 + wr * 128 + mi * 16 + fq * 4 + j;
                const int cg = n0 + wc * 32 + ni * 16 + fr;
                float v = acc[mi][ni][j];
                if (MODE == 0) {
                    v += (cg < 2048) ? b0[cg] : ((cg < 4096) ? b1[cg - 2048] : b2[cg - 4096]);
                    if (cg < 4096) {  // block-uniform: RoPE on Q and K
                        const int s = r & (SEQ - 1);
                        const int i = (cg >> 1) & 63;
                        const float cs = fcos[s * 64 + i];
                        const float sn = fsin[s * 64 + i];
                        const float p  = __shfl_xor(v, 1);
                        v = (fr & 1) ? (p * sn + v * cs) : (v * cs - p * sn);
                    }
                    ((unsigned short*)C)[(size_t)r * ldc + cg] = f2bf(v);
                } else {
                    v += b0[cg];
                    ((float*)C)[(size_t)r * ldc + cg] = v;
                }
            }
        }
    }
}

#undef KTILE
#undef TR2
#undef TR0
#undef TRN
#undef PH_MFMA
#undef PH_BAR
#undef STAGE_A
#undef STAGE_B
#undef LA
#undef LB

// ---------------- 128x128 GEMM core (small GEMMs) ----------------
template<int OUT_BF16, int HAS_BIAS>
__device__ __forceinline__ void gemm_tile_core(
    const unsigned short* __restrict__ A, int lda,
    const unsigned short* __restrict__ B, int ldb,
    const float* __restrict__ bias,
    void* __restrict__ Cptr, int ldc, int K)
{
    __shared__ __align__(16) unsigned short As[128 * 64];
    __shared__ __align__(16) unsigned short Bs[128 * 64];

    const int t  = threadIdx.x;
    const int l  = t & 63;
    const int w  = t >> 6;
    const int wr = w >> 1, wc = w & 1;
    const int fr = l & 15, fq = l >> 4;

    f32x4 acc[4][4] = {};

    const int srow = t >> 3;
    const int scol = (t & 7) * 8;

    for (int k0 = 0; k0 < K; k0 += 64) {
        __syncthreads();
        #pragma unroll
        for (int r = 0; r < 4; ++r) {
            gld_lds16(A + (size_t)(r * 32 + srow) * lda + k0 + scol, &As[(r * 32 + srow) * 64 + scol]);
            gld_lds16(B + (size_t)(r * 32 + srow) * ldb + k0 + scol, &Bs[(r * 32 + srow) * 64 + scol]);
        }
        __syncthreads();
        #pragma unroll
        for (int kk = 0; kk < 2; ++kk) {
            short8 a[4], b[4];
            #pragma unroll
            for (int mi = 0; mi < 4; ++mi)
                a[mi] = *(const short8*)&As[(wr * 64 + mi * 16 + fr) * 64 + kk * 32 + fq * 8];
            #pragma unroll
            for (int ni = 0; ni < 4; ++ni)
                b[ni] = *(const short8*)&Bs[(wc * 64 + ni * 16 + fr) * 64 + kk * 32 + fq * 8];
            #pragma unroll
            for (int mi = 0; mi < 4; ++mi)
                #pragma unroll
                for (int ni = 0; ni < 4; ++ni)
                    acc[mi][ni] = __builtin_amdgcn_mfma_f32_16x16x32_bf16(a[mi], b[ni], acc[mi][ni], 0, 0, 0);
        }
    }

    #pragma unroll
    for (int mi = 0; mi < 4; ++mi) {
        #pragma unroll
        for (int ni = 0; ni < 4; ++ni) {
            #pragma unroll
            for (int j = 0; j < 4; ++j) {
                int rr = wr * 64 + mi * 16 + fq * 4 + j;
                int cc = wc * 64 + ni * 16 + fr;
                float v = acc[mi][ni][j];
                if (HAS_BIAS) v += bias[cc];
                if (OUT_BF16) ((unsigned short*)Cptr)[(size_t)rr * ldc + cc] = f2bf(v);
                else          ((float*)Cptr)[(size_t)rr * ldc + cc] = v;
            }
        }
    }
}

// ---------------- K^T/V partials: part[bh][ks][d1][d2] = sum_s K[s][d1]*V[s][d2] ----------------
__global__ __launch_bounds__(256) void ktv_kernel(
    const unsigned short* __restrict__ QKV, float* __restrict__ part)
{
    const int ks = blockIdx.x;  // 0..7
    const int bh = blockIdx.y;  // 0..31
    const int b = bh >> 4, h = bh & 15;
    const unsigned short* Kbase = QKV + (size_t)(b * SEQ + ks * 256) * NQKV + 2048 + h * HD;
    const unsigned short* Vbase = QKV + (size_t)(b * SEQ + ks * 256) * NQKV + 4096 + h * HD;

    __shared__ __align__(16) unsigned short Ks_[64 * 128];
    __shared__ __align__(16) unsigned short Vs_[64 * 128];

    const int t  = threadIdx.x;
    const int l  = t & 63;
    const int w  = t >> 6;
    const int wr = w >> 1, wc = w & 1;
    const int fr = l & 15, fq = l >> 4;

    f32x4 acc[4][4] = {};

    const int srow = t >> 4;
    const int scol = (t & 15) * 8;

    for (int sc = 0; sc < 4; ++sc) {
        __syncthreads();
        #pragma unroll
        for (int r = 0; r < 4; ++r) {
            gld_lds16(Kbase + (size_t)(sc * 64 + r * 16 + srow) * NQKV + scol, &Ks_[(r * 16 + srow) * 128 + scol]);
            gld_lds16(Vbase + (size_t)(sc * 64 + r * 16 + srow) * NQKV + scol, &Vs_[(r * 16 + srow) * 128 + scol]);
        }
        __syncthreads();
        #pragma unroll
        for (int kk = 0; kk < 2; ++kk) {
            short8 a[4], bb[4];
            #pragma unroll
            for (int mi = 0; mi < 4; ++mi)      // A = K  (m index = d1)
                #pragma unroll
                for (int i = 0; i < 8; ++i)
                    a[mi][i] = (short)Ks_[(kk * 32 + fq * 8 + i) * 128 + wr * 64 + mi * 16 + fr];
            #pragma unroll
            for (int ni = 0; ni < 4; ++ni)      // B = V  (n index = d2)
                #pragma unroll
                for (int i = 0; i < 8; ++i)
                    bb[ni][i] = (short)Vs_[(kk * 32 + fq * 8 + i) * 128 + wc * 64 + ni * 16 + fr];
            #pragma unroll
            for (int mi = 0; mi < 4; ++mi)
                #pragma unroll
                for (int ni = 0; ni < 4; ++ni)
                    acc[mi][ni] = __builtin_amdgcn_mfma_f32_16x16x32_bf16(a[mi], bb[ni], acc[mi][ni], 0, 0, 0);
        }
    }

    float* base = part + ((size_t)bh * 8 + ks) * 16384;
    #pragma unroll
    for (int mi = 0; mi < 4; ++mi)
        #pragma unroll
        for (int ni = 0; ni < 4; ++ni)
            #pragma unroll
            for (int j = 0; j < 4; ++j)
                base[(wr * 64 + mi * 16 + fq * 4 + j) * 128 + wc * 64 + ni * 16 + fr] = acc[mi][ni][j];
}

// ---------------- reduce partials, scale, -> bf16 M2t[bh][d1][d2] ----------------
__global__ void ktv_reduce(const float* __restrict__ part, unsigned short* __restrict__ M2t) {
    int idx = blockIdx.x * 256 + threadIdx.x;
    int bh = idx >> 14, rem = idx & 16383;
    const float* p = part + ((size_t)bh * 8) * 16384 + rem;
    float s = 0.f;
    #pragma unroll
    for (int k = 0; k < 8; ++k) s += p[(size_t)k * 16384];
    M2t[idx] = f2bf(s * 0.08838834764831845f);  // 1/sqrt(128)
}

// ---------------- W2[b][i][h*128+d1] = sum_d2 Wo[i][h*128+d2] * M2t[bh][d1][d2] ----------------
__global__ __launch_bounds__(256) void w2_gemm(
    const unsigned short* __restrict__ Wo2, const unsigned short* __restrict__ M2t,
    unsigned short* __restrict__ W2)
{
    const int mt = blockIdx.x;   // 0..15
    const int bh = blockIdx.y;   // 0..31
    const int b = bh >> 4, h = bh & 15;
    const unsigned short* A = Wo2 + (size_t)(mt * 128) * DIMN + h * HD;
    const unsigned short* B = M2t + (size_t)bh * HD * HD;
    unsigned short* Cp = W2 + (size_t)b * DIMN * DIMN + (size_t)(mt * 128) * DIMN + h * HD;
    gemm_tile_core<1, 0>(A, DIMN, B, HD, nullptr, Cp, DIMN, HD);
}

extern "C" void kernel_launch(void* const* d_in, const int* in_sizes, int n_in,
                              void* d_out, int out_size, void* d_ws, size_t ws_size,
                              hipStream_t stream) {
    const float* x    = (const float*)d_in[0];
    const float* fcos = (const float*)d_in[1];
    const float* fsin = (const float*)d_in[2];
    const float* wq   = (const float*)d_in[3];
    const float* bq   = (const float*)d_in[4];
    const float* wk   = (const float*)d_in[5];
    const float* bk   = (const float*)d_in[6];
    const float* wv   = (const float*)d_in[7];
    const float* bv   = (const float*)d_in[8];
    const float* wo   = (const float*)d_in[9];
    const float* bo   = (const float*)d_in[10];
    float* out = (float*)d_out;

    char* ws = (char*)d_ws;
    size_t off = 0;
    auto alloc = [&](size_t bytes) { char* p = ws + off; off += (bytes + 255) & ~(size_t)255; return p; };

    unsigned short* Xb   = (unsigned short*)alloc((size_t)ROWS * DIMN * 2);
    unsigned short* Wcat = (unsigned short*)alloc((size_t)NQKV * DIMN * 2);
    unsigned short* Wo2  = (unsigned short*)alloc((size_t)DIMN * DIMN * 2);
    unsigned short* QKV  = (unsigned short*)alloc((size_t)ROWS * NQKV * 2);
    float*          part = (float*)alloc((size_t)32 * 8 * HD * HD * 4);
    unsigned short* M2t  = (unsigned short*)alloc((size_t)32 * HD * HD * 2);
    unsigned short* W2   = (unsigned short*)alloc((size_t)BSZ * DIMN * DIMN * 2);

    // all converts in one launch
    cvt_all<<<24576, 256, 0, stream>>>(x, wq, wk, wv, wo, Xb, Wcat, Wo2);

    // fused QKV projection + bias + RoPE  (M=4096, N=6144, K=2048): 48x16 = 768 blocks = 3 rounds
    gemm_p4<0><<<dim3(NQKV / 128, ROWS / 256), 512, 0, stream>>>(
        Xb, DIMN, Wcat, DIMN, bq, bk, bv, fcos, fsin, QKV, NQKV, DIMN);

    // reassociated attention (no softmax): M2t = (K^T V)^T/sqrt(d) per (b,h)
    ktv_kernel<<<dim3(8, 32), 256, 0, stream>>>(QKV, part);
    ktv_reduce<<<(32 * 16384) / 256, 256, 0, stream>>>(part, M2t);

    // fold attention + output projection: W2_b = concat_h(Wo_h @ M2_{b,h})
    w2_gemm<<<dim3(16, 32), 256, 0, stream>>>(Wo2, M2t, W2);

    // out = Q @ W2_b^T + bo  (M=4096, N=2048, K=2048): 16x16 = 256 blocks = 1 round
    gemm_p4<1><<<dim3(DIMN / 128, ROWS / 256), 512, 0, stream>>>(
        QKV, NQKV, W2, DIMN, bo, nullptr, nullptr, nullptr, nullptr, out, DIMN, DIMN);
}